// Round 11
// baseline (81.389 us; speedup 1.0000x reference)
//
#include <hip/hip_runtime.h>

#define N_KER 64
#define K_PTS 16
#define LOG2E 1.44269504088896340736f

// ============================================================================
// out[i][m] = (1/128) * (S[i][m]+S[a][m]+S[b][m]+S[c][m]),
// S[q][m] = sum_l exp(-||g_q - k[m][l]||^2), S stored u8 (absmax 1.22e-3 vs
// threshold 3.4e-3, margin 2.8x).
// R11: phase1 = R8 VERBATIM (measured best; R10's 8pt/wave reverted).
// phase2: 4 threads/point, uint4 row-segment loads (same bytes, 1/4 the load
// instructions and blocks), identical integer byte-lane math.
// Dead ends (do not retry): cooperative grid.sync (R9: 420us spin),
// two-step LDS staging (R7: repack read hits 2 banks -> 32-way conflict),
// >64 VGPR (R3: occupancy 4x drop), 8pt/wave phase1 (R10: flat/worse).
// ============================================================================

// ---- Phase 1: S[q][m] u8; lane = m; 4 waves x 4 points per block (R8) ----
__global__ __launch_bounds__(256, 8) void corr_phase1(
    const float*   __restrict__ normal,
    const float*   __restrict__ kern,
    unsigned char* __restrict__ S,
    int n)
{
    __shared__ float4 ksp[K_PTS * N_KER];   // 16 KB [l][m], conflict-free (R3+)

    const int tid = threadIdx.x;
    #pragma unroll
    for (int it = 0; it < 4; ++it) {
        int j = it * 256 + tid;            // 0..1023 -> (l,m)
        int m = j & 63;
        int l = j >> 6;
        const float* kp = kern + (m * K_PTS + l) * 3;
        float x = kp[0], y = kp[1], z = kp[2];
        ksp[l * N_KER + m] = make_float4(2.0f * LOG2E * x,
                                         2.0f * LOG2E * y,
                                         2.0f * LOG2E * z,
                                         -LOG2E * (x * x + y * y + z * z));
    }
    __syncthreads();

    const int wave = tid >> 6;
    const int m    = tid & 63;
    const int q0   = blockIdx.x * 16 + wave * 4;   // 4 points per wave

    float gx[4], gy[4], gz[4], ea[4], acc[4];
    #pragma unroll
    for (int p = 0; p < 4; ++p) {
        int q = min(q0 + p, n - 1);
        float x = normal[q * 3 + 0];    // wave-uniform -> broadcast loads
        float y = normal[q * 3 + 1];
        float z = normal[q * 3 + 2];
        gx[p] = x; gy[p] = y; gz[p] = z;
        ea[p] = __builtin_amdgcn_exp2f(-LOG2E * (x * x + y * y + z * z));
        acc[p] = 0.0f;
    }

    #pragma unroll 4
    for (int l = 0; l < K_PTS; ++l) {
        float4 k4 = ksp[l * N_KER + m];
        #pragma unroll
        for (int p = 0; p < 4; ++p)
            acc[p] += __builtin_amdgcn_exp2f(
                fmaf(gx[p], k4.x, fmaf(gy[p], k4.y, fmaf(gz[p], k4.z, k4.w))));
    }

    const float QS = 255.0f / 16.0f;
    #pragma unroll
    for (int p = 0; p < 4; ++p)
        if (q0 + p < n) {
            float v = ea[p] * acc[p];
            S[(size_t)(q0 + p) * N_KER + m] = (unsigned char)(v * QS + 0.5f);
        }
}

// ---- Phase 2: 4 threads/point; each thread loads one 16B segment (uint4)
// of 4 rows, sums byte lanes as exact integers, stores 4x float4. ----
__global__ __launch_bounds__(256) void corr_phase2(
    const uint4* __restrict__ S16,           // u8 rows viewed as 4 uint4/row
    const int*   __restrict__ neighbour,
    float4*      __restrict__ out4,
    int n)
{
    int t = blockIdx.x * 256 + threadIdx.x;  // segment index == i*4 + h
    if (t >= n * 4) return;
    int i = t >> 2;
    int h = t & 3;
    int a = neighbour[i * 3 + 0];
    int b = neighbour[i * 3 + 1];
    int c = neighbour[i * 3 + 2];
    uint4 w0 = S16[t];                       // self: coalesced
    uint4 w1 = S16[a * 4 + h];               // 16B of a 64B L2-resident row
    uint4 w2 = S16[b * 4 + h];
    uint4 w3 = S16[c * 4 + h];
    const float DQ = (16.0f / 255.0f) / 128.0f;

    unsigned int ww0[4] = { w0.x, w0.y, w0.z, w0.w };
    unsigned int ww1[4] = { w1.x, w1.y, w1.z, w1.w };
    unsigned int ww2[4] = { w2.x, w2.y, w2.z, w2.w };
    unsigned int ww3[4] = { w3.x, w3.y, w3.z, w3.w };

    #pragma unroll
    for (int k = 0; k < 4; ++k) {            // 4 u32 words -> 4 float4 stores
        unsigned int u0 = ww0[k], u1 = ww1[k], u2 = ww2[k], u3 = ww3[k];
        float4 r;
        r.x = (float)(( u0        & 255u) + ( u1        & 255u) +
                      ( u2        & 255u) + ( u3        & 255u)) * DQ;
        r.y = (float)(((u0 >>  8) & 255u) + ((u1 >>  8) & 255u) +
                      ((u2 >>  8) & 255u) + ((u3 >>  8) & 255u)) * DQ;
        r.z = (float)(((u0 >> 16) & 255u) + ((u1 >> 16) & 255u) +
                      ((u2 >> 16) & 255u) + ((u3 >> 16) & 255u)) * DQ;
        r.w = (float)(( u0 >> 24        ) + ( u1 >> 24        ) +
                      ( u2 >> 24        ) + ( u3 >> 24        )) * DQ;
        out4[t * 4 + k] = r;
    }
}

// ---- Fallback (R4 fused kernel, proven) if ws too small ----
__global__ __launch_bounds__(256, 8) void corr_fused(
    const float* __restrict__ normal,
    const int*   __restrict__ neighbour,
    const float* __restrict__ kern,
    float*       __restrict__ out,
    int n)
{
    __shared__ float4 ksp[K_PTS * N_KER];
    const int tid = threadIdx.x;
    #pragma unroll
    for (int it = 0; it < 4; ++it) {
        int j = it * 256 + tid;
        int m = j & 63;
        int l = j >> 6;
        const float* kp = kern + (m * K_PTS + l) * 3;
        float x = kp[0], y = kp[1], z = kp[2];
        ksp[l * N_KER + m] = make_float4(2.0f * LOG2E * x, 2.0f * LOG2E * y,
                                         2.0f * LOG2E * z,
                                         -LOG2E * (x * x + y * y + z * z));
    }
    __syncthreads();
    const int wave = tid >> 6;
    const int m    = tid & 63;
    const int i    = blockIdx.x * 4 + wave;
    if (i >= n) return;
    const int ia = neighbour[i * 3 + 0];
    const int ib = neighbour[i * 3 + 1];
    const int ic = neighbour[i * 3 + 2];
    int idxs[4] = { i, ia, ib, ic };
    float gx[4], gy[4], gz[4], ea[4], acc[4];
    #pragma unroll
    for (int p = 0; p < 4; ++p) {
        int q = idxs[p];
        float x = normal[q * 3 + 0];
        float y = normal[q * 3 + 1];
        float z = normal[q * 3 + 2];
        gx[p] = x; gy[p] = y; gz[p] = z;
        ea[p] = __builtin_amdgcn_exp2f(-LOG2E * (x * x + y * y + z * z));
        acc[p] = 0.0f;
    }
    #pragma unroll 4
    for (int l = 0; l < K_PTS; ++l) {
        float4 k4 = ksp[l * N_KER + m];
        #pragma unroll
        for (int p = 0; p < 4; ++p)
            acc[p] += __builtin_amdgcn_exp2f(
                fmaf(gx[p], k4.x, fmaf(gy[p], k4.y, fmaf(gz[p], k4.z, k4.w))));
    }
    float s = ea[0] * acc[0] + ea[1] * acc[1] + ea[2] * acc[2] + ea[3] * acc[3];
    out[(size_t)i * N_KER + m] = s * (1.0f / 128.0f);
}

extern "C" void kernel_launch(void* const* d_in, const int* in_sizes, int n_in,
                              void* d_out, int out_size, void* d_ws, size_t ws_size,
                              hipStream_t stream) {
    const float* normal    = (const float*)d_in[0];
    const int*   neighbour = (const int*)d_in[1];
    const float* kern      = (const float*)d_in[2];
    float*       out       = (float*)d_out;

    int n = in_sizes[0] / 3;
    size_t need = (size_t)n * N_KER;               // u8 table bytes

    if (ws_size >= need) {
        unsigned char* S = (unsigned char*)d_ws;
        int blocks1 = (n + 15) / 16;               // 4 q/wave, 4 waves (R8)
        corr_phase1<<<blocks1, 256, 0, stream>>>(normal, kern, S, n);
        int blocks2 = (n * 4 + 255) / 256;         // 4 threads/point
        corr_phase2<<<blocks2, 256, 0, stream>>>((const uint4*)S,
                                                 neighbour, (float4*)out, n);
    } else {
        int blocks = (n + 3) / 4;
        corr_fused<<<blocks, 256, 0, stream>>>(normal, neighbour, kern, out, n);
    }
}

// Round 12
// 78.676 us; speedup vs baseline: 1.0345x; 1.0345x over previous
//
#include <hip/hip_runtime.h>

#define N_KER 64
#define K_PTS 16
#define LOG2E 1.44269504088896340736f

// ============================================================================
// FINAL (R8 verbatim — best measured: 78.7 us total, absmax 1.22e-3 vs
// threshold 3.4e-3).
// out[i][m] = (1/128) * (S[i][m]+S[a][m]+S[b][m]+S[c][m]),
// S[q][m] = sum_l exp(-||g_q - k[m][l]||^2), S stored u8 in d_ws.
//
// Optimization ladder (measured):
//   R2 naive-par 89us -> R3 conflict-free float4 LDS table (+exp2-fold,
//   bank conflicts 3.7e7->0) 50 -> R4 VGPR<=64 (occupancy 26->66%) 47 ->
//   R5 two-phase S-table dedup (204.8M->51.2M exps) ~38 -> R6 f16 S ~32 ->
//   R8 u8 S ~29 controllable + ~50us invariant harness fill floor.
// Dead ends (measured, do not retry): cooperative grid.sync fusion (R9:
// 420us barrier spin at 93% occupancy / 2.5% VALUBusy), two-step LDS
// staging repack (R7: 32-way bank conflict on repack read), >64 VGPR (R3),
// 8pt/wave phase1 (R10), uint4 phase2 (R11) — all flat-to-worse.
// Remaining structure: phase1 ~11us issue-bound (trans floor ~5),
// phase2 ~5us L2-gather-bound, ~10us dispatch structure, ~50us harness
// poison fills at 78% HBM peak. All remaining levers are sub-noise (+-2us).
// ============================================================================

// ---- Phase 1: S[q][m] u8; lane = m; 4 waves x 4 points per block ----
__global__ __launch_bounds__(256, 8) void corr_phase1(
    const float*   __restrict__ normal,
    const float*   __restrict__ kern,
    unsigned char* __restrict__ S,
    int n)
{
    __shared__ float4 ksp[K_PTS * N_KER];   // 16 KB [l][m], conflict-free (R3+)

    const int tid = threadIdx.x;
    #pragma unroll
    for (int it = 0; it < 4; ++it) {
        int j = it * 256 + tid;            // 0..1023 -> (l,m)
        int m = j & 63;
        int l = j >> 6;
        const float* kp = kern + (m * K_PTS + l) * 3;
        float x = kp[0], y = kp[1], z = kp[2];
        ksp[l * N_KER + m] = make_float4(2.0f * LOG2E * x,
                                         2.0f * LOG2E * y,
                                         2.0f * LOG2E * z,
                                         -LOG2E * (x * x + y * y + z * z));
    }
    __syncthreads();

    const int wave = tid >> 6;
    const int m    = tid & 63;
    const int q0   = blockIdx.x * 16 + wave * 4;   // 4 points per wave

    float gx[4], gy[4], gz[4], ea[4], acc[4];
    #pragma unroll
    for (int p = 0; p < 4; ++p) {
        int q = min(q0 + p, n - 1);
        float x = normal[q * 3 + 0];    // wave-uniform -> broadcast loads
        float y = normal[q * 3 + 1];
        float z = normal[q * 3 + 2];
        gx[p] = x; gy[p] = y; gz[p] = z;
        ea[p] = __builtin_amdgcn_exp2f(-LOG2E * (x * x + y * y + z * z));
        acc[p] = 0.0f;
    }

    // 16 l-steps x 4 points: 1 ds_read_b128 -> 4 exps; unroll 4 keeps
    // VGPR < 64 (R3 lesson: crossing 64 halves occupancy).
    #pragma unroll 4
    for (int l = 0; l < K_PTS; ++l) {
        float4 k4 = ksp[l * N_KER + m];
        #pragma unroll
        for (int p = 0; p < 4; ++p)
            acc[p] += __builtin_amdgcn_exp2f(
                fmaf(gx[p], k4.x, fmaf(gy[p], k4.y, fmaf(gz[p], k4.z, k4.w))));
    }

    // u8 quantize: v in (0,16], q = v*255/16 + 0.5 truncated; 64 contiguous
    // byte stores per wave per point -> one 64B txn.
    const float QS = 255.0f / 16.0f;
    #pragma unroll
    for (int p = 0; p < 4; ++p)
        if (q0 + p < n) {
            float v = ea[p] * acc[p];
            S[(size_t)(q0 + p) * N_KER + m] = (unsigned char)(v * QS + 0.5f);
        }
}

// ---- Phase 2: 16 threads/point; each thread: 4 u32 row-word loads,
// exact integer sums per byte lane, one dequant mul, float4 store. ----
__global__ __launch_bounds__(256) void corr_phase2(
    const unsigned int* __restrict__ S4,     // u8 rows viewed as 16 u32 words
    const int*          __restrict__ neighbour,
    float4*             __restrict__ out4,
    int n)
{
    int t = blockIdx.x * 256 + threadIdx.x;  // word index == i*16 + h
    if (t >= n * 16) return;
    int i = t >> 4;
    int a = neighbour[i * 3 + 0];
    int b = neighbour[i * 3 + 1];
    int c = neighbour[i * 3 + 2];
    int h = t & 15;
    unsigned int w0 = S4[t];                 // self: coalesced
    unsigned int w1 = S4[a * 16 + h];        // 64B row segments, L2-resident
    unsigned int w2 = S4[b * 16 + h];
    unsigned int w3 = S4[c * 16 + h];
    const float DQ = (16.0f / 255.0f) / 128.0f;
    float4 r;
    r.x = (float)(( w0        & 255u) + ( w1        & 255u) +
                  ( w2        & 255u) + ( w3        & 255u)) * DQ;
    r.y = (float)(((w0 >>  8) & 255u) + ((w1 >>  8) & 255u) +
                  ((w2 >>  8) & 255u) + ((w3 >>  8) & 255u)) * DQ;
    r.z = (float)(((w0 >> 16) & 255u) + ((w1 >> 16) & 255u) +
                  ((w2 >> 16) & 255u) + ((w3 >> 16) & 255u)) * DQ;
    r.w = (float)(( w0 >> 24        ) + ( w1 >> 24        ) +
                  ( w2 >> 24        ) + ( w3 >> 24        )) * DQ;
    out4[t] = r;
}

// ---- Fallback (R4 fused kernel, proven) if ws too small ----
__global__ __launch_bounds__(256, 8) void corr_fused(
    const float* __restrict__ normal,
    const int*   __restrict__ neighbour,
    const float* __restrict__ kern,
    float*       __restrict__ out,
    int n)
{
    __shared__ float4 ksp[K_PTS * N_KER];
    const int tid = threadIdx.x;
    #pragma unroll
    for (int it = 0; it < 4; ++it) {
        int j = it * 256 + tid;
        int m = j & 63;
        int l = j >> 6;
        const float* kp = kern + (m * K_PTS + l) * 3;
        float x = kp[0], y = kp[1], z = kp[2];
        ksp[l * N_KER + m] = make_float4(2.0f * LOG2E * x, 2.0f * LOG2E * y,
                                         2.0f * LOG2E * z,
                                         -LOG2E * (x * x + y * y + z * z));
    }
    __syncthreads();
    const int wave = tid >> 6;
    const int m    = tid & 63;
    const int i    = blockIdx.x * 4 + wave;
    if (i >= n) return;
    const int ia = neighbour[i * 3 + 0];
    const int ib = neighbour[i * 3 + 1];
    const int ic = neighbour[i * 3 + 2];
    int idxs[4] = { i, ia, ib, ic };
    float gx[4], gy[4], gz[4], ea[4], acc[4];
    #pragma unroll
    for (int p = 0; p < 4; ++p) {
        int q = idxs[p];
        float x = normal[q * 3 + 0];
        float y = normal[q * 3 + 1];
        float z = normal[q * 3 + 2];
        gx[p] = x; gy[p] = y; gz[p] = z;
        ea[p] = __builtin_amdgcn_exp2f(-LOG2E * (x * x + y * y + z * z));
        acc[p] = 0.0f;
    }
    #pragma unroll 4
    for (int l = 0; l < K_PTS; ++l) {
        float4 k4 = ksp[l * N_KER + m];
        #pragma unroll
        for (int p = 0; p < 4; ++p)
            acc[p] += __builtin_amdgcn_exp2f(
                fmaf(gx[p], k4.x, fmaf(gy[p], k4.y, fmaf(gz[p], k4.z, k4.w))));
    }
    float s = ea[0] * acc[0] + ea[1] * acc[1] + ea[2] * acc[2] + ea[3] * acc[3];
    out[(size_t)i * N_KER + m] = s * (1.0f / 128.0f);
}

extern "C" void kernel_launch(void* const* d_in, const int* in_sizes, int n_in,
                              void* d_out, int out_size, void* d_ws, size_t ws_size,
                              hipStream_t stream) {
    const float* normal    = (const float*)d_in[0];
    const int*   neighbour = (const int*)d_in[1];
    const float* kern      = (const float*)d_in[2];
    float*       out       = (float*)d_out;

    int n = in_sizes[0] / 3;
    size_t need = (size_t)n * N_KER;               // u8 table bytes

    if (ws_size >= need) {
        unsigned char* S = (unsigned char*)d_ws;
        int blocks1 = (n + 15) / 16;               // 4 q/wave, 4 waves (R8)
        corr_phase1<<<blocks1, 256, 0, stream>>>(normal, kern, S, n);
        int blocks2 = (n * 16 + 255) / 256;
        corr_phase2<<<blocks2, 256, 0, stream>>>((const unsigned int*)S,
                                                 neighbour, (float4*)out, n);
    } else {
        int blocks = (n + 3) / 4;
        corr_fused<<<blocks, 256, 0, stream>>>(normal, neighbour, kern, out, n);
    }
}